// Round 2
// baseline (226.219 us; speedup 1.0000x reference)
//
#include <hip/hip_runtime.h>
#include <stdint.h>

#define NB 2
#define NH 16
#define SEQ 4096
#define DD 64
#define NM 16           // 256-row query blocks per head
#define QB 256
#define CH 256          // keys per chunk
#define VSTR 528        // V^T LDS row stride in bytes (256*2 + 16 pad -> 4-way max conflict)

typedef __attribute__((ext_vector_type(8)))  __bf16 bf16x8;
typedef __attribute__((ext_vector_type(16))) float  f32x16;
typedef __attribute__((ext_vector_type(2)))  unsigned int u32x2;

static __device__ __forceinline__ f32x16 zero16() {
    f32x16 z;
#pragma unroll
    for (int i = 0; i < 16; i++) z[i] = 0.0f;
    return z;
}

__global__ void __launch_bounds__(512, 2)
swa_kernel(const float* __restrict__ Q, const float* __restrict__ K,
           const float* __restrict__ V, const float* __restrict__ scale_p,
           float* __restrict__ out)
{
    // XCD-aware swizzle: 512 blocks, 512 % 8 == 0 -> simple bijective remap.
    int lid = (int)blockIdx.x;
    lid = (lid & 7) * 64 + (lid >> 3);
    const int m  = lid & 15;        // query block
    const int bh = lid >> 4;        // b*NH + h

    const float scale = scale_p[0];
    const float* Qb = Q + (size_t)bh * SEQ * DD;
    const float* Kb = K + (size_t)bh * SEQ * DD;
    const float* Vb = V + (size_t)bh * SEQ * DD;
    float*       Ob = out + (size_t)bh * SEQ * DD;

    const int tid  = threadIdx.x;
    const int lane = tid & 63;
    const int w    = tid >> 6;      // wave 0..7
    const int l31  = lane & 31;
    const int h5   = lane >> 5;

    __shared__ __align__(16) unsigned char vt[64 * VSTR];   // V^T chunk: [d=64][key=256] bf16

    // ---- Q fragments (B operand of swapped QK^T): lane holds Q[q=l31][16s + 8*h5 + e]
    bf16x8 qf[4];
    {
        const float* qp = Qb + (size_t)(m * QB + w * 32 + l31) * DD + 8 * h5;
#pragma unroll
        for (int s = 0; s < 4; s++) {
            float4 a = *(const float4*)(qp + 16 * s);
            float4 b = *(const float4*)(qp + 16 * s + 4);
            bf16x8 f;
            f[0] = (__bf16)a.x; f[1] = (__bf16)a.y; f[2] = (__bf16)a.z; f[3] = (__bf16)a.w;
            f[4] = (__bf16)b.x; f[5] = (__bf16)b.y; f[6] = (__bf16)b.z; f[7] = (__bf16)b.w;
            qf[s] = f;
        }
    }

    f32x16 accA0 = zero16(), accA1 = zero16();   // window A numerator (cols 0-31 / 32-63)
    f32x16 accB0 = zero16(), accB1 = zero16();   // window B numerator
    float dA = 0.0f, dB = 0.0f;                  // per-lane denominator partials

    for (int ci = 0; ci < 3; ci++) {
        const int ck = (m - 1 + ci) * CH;
        if (ck < 0 || ck >= SEQ) continue;
        const bool inA = (m > 0) && (ci <= 1);   // window A = chunks 0,1
        const bool inB = (ci >= 1);              // window B = chunks 1,2 (m=15: chunk 1 only)

        __syncthreads();
        // ---- stage V^T chunk into LDS as bf16 (transpose): vt[d][key]
        {
            const int kk = (tid & 127) * 2;      // key pair
            const int dg = tid >> 7;             // 0..3 -> d block of 16
            const float* vp0 = Vb + (size_t)(ck + kk) * DD + dg * 16;
            const float* vp1 = vp0 + DD;
#pragma unroll
            for (int j = 0; j < 16; j += 4) {
                float4 a = *(const float4*)(vp0 + j);
                float4 b = *(const float4*)(vp1 + j);
                float av[4] = {a.x, a.y, a.z, a.w};
                float bv[4] = {b.x, b.y, b.z, b.w};
#pragma unroll
                for (int e = 0; e < 4; e++) {
                    union { __bf16 h[2]; uint32_t u; } pk;
                    pk.h[0] = (__bf16)av[e];
                    pk.h[1] = (__bf16)bv[e];
                    *(uint32_t*)(vt + (size_t)(dg * 16 + j + e) * VSTR + kk * 2) = pk.u;
                }
            }
        }
        __syncthreads();

        // ---- 8 key tiles of 32
        for (int kt = 0; kt < 8; kt++) {
            // K fragment (A operand): lane holds K[ck+kt*32+l31][16s + 8*h5 + e]
            const float* kp = Kb + (size_t)(ck + kt * 32 + l31) * DD + 8 * h5;
            f32x16 st = zero16();
#pragma unroll
            for (int s = 0; s < 4; s++) {
                float4 a = *(const float4*)(kp + 16 * s);
                float4 b = *(const float4*)(kp + 16 * s + 4);
                bf16x8 f;
                f[0] = (__bf16)a.x; f[1] = (__bf16)a.y; f[2] = (__bf16)a.z; f[3] = (__bf16)a.w;
                f[4] = (__bf16)b.x; f[5] = (__bf16)b.y; f[6] = (__bf16)b.z; f[7] = (__bf16)b.w;
                st = __builtin_amdgcn_mfma_f32_32x32x16_bf16(f, qf[s], st, 0, 0, 0);
            }
            // st = S^T tile: col(lane&31)=q, row=(r&3)+8*(r>>2)+4*h5 = key

            // ---- sigmoid, bf16 round, per-lane denominator
            uint32_t wv[8];
            float dsum = 0.0f;
#pragma unroll
            for (int i = 0; i < 8; i++) {
                float e0 = __expf(-st[2 * i] * scale);
                float e1 = __expf(-st[2 * i + 1] * scale);
                float p0 = __builtin_amdgcn_rcpf(1.0f + e0);
                float p1 = __builtin_amdgcn_rcpf(1.0f + e1);
                union { __bf16 h[2]; uint32_t u; } pk;
                pk.h[0] = (__bf16)p0;
                pk.h[1] = (__bf16)p1;
                wv[i] = pk.u;
                dsum += (float)pk.h[0] + (float)pk.h[1];   // denom from rounded P (consistency)
            }
            if (inA) dA += dsum;
            if (inB) dB += dsum;

            // ---- P relayout: C-layout -> A-fragments via permlane32_swap
            // HW semantics (T12 recipe): swap(x,y) -> ret[0] = {x.lo | y.lo},
            // ret[1] = {x.hi | y.hi}  (vdst.row1 <-> vsrc.row0).
            // wv[i] holds keys: wv[0]=(0,1)+4h5 wv[1]=(2,3)+4h5 wv[2]=(8,9)+4h5
            // wv[3]=(10,11)+4h5 wv[4..7]= same +16.
            u32x2 rA = __builtin_amdgcn_permlane32_swap(wv[0], wv[2], false, false);
            u32x2 rB = __builtin_amdgcn_permlane32_swap(wv[1], wv[3], false, false);
            u32x2 rC = __builtin_amdgcn_permlane32_swap(wv[4], wv[6], false, false);
            u32x2 rD = __builtin_amdgcn_permlane32_swap(wv[5], wv[7], false, false);
            union { uint32_t u[4]; bf16x8 v; } A0, A1;
            A0.u[0] = rA[0]; A0.u[1] = rB[0]; A0.u[2] = rA[1]; A0.u[3] = rB[1]; // keys 8h5+{0..7}
            A1.u[0] = rC[0]; A1.u[1] = rD[0]; A1.u[2] = rC[1]; A1.u[3] = rD[1]; // keys 16+8h5+{0..7}

            // ---- V fragments from LDS (B operand): lane holds V^T[d=32t+l31][k..k+7]
            const unsigned char* vrow0 = vt + (size_t)l31 * VSTR;
            const unsigned char* vrow1 = vt + (size_t)(32 + l31) * VSTR;
            const int ko = kt * 64 + h5 * 16;
            bf16x8 v00 = *(const bf16x8*)(vrow0 + ko);
            bf16x8 v01 = *(const bf16x8*)(vrow0 + ko + 32);
            bf16x8 v10 = *(const bf16x8*)(vrow1 + ko);
            bf16x8 v11 = *(const bf16x8*)(vrow1 + ko + 32);

            if (inA) {
                accA0 = __builtin_amdgcn_mfma_f32_32x32x16_bf16(A0.v, v00, accA0, 0, 0, 0);
                accA0 = __builtin_amdgcn_mfma_f32_32x32x16_bf16(A1.v, v01, accA0, 0, 0, 0);
                accA1 = __builtin_amdgcn_mfma_f32_32x32x16_bf16(A0.v, v10, accA1, 0, 0, 0);
                accA1 = __builtin_amdgcn_mfma_f32_32x32x16_bf16(A1.v, v11, accA1, 0, 0, 0);
            }
            if (inB) {
                accB0 = __builtin_amdgcn_mfma_f32_32x32x16_bf16(A0.v, v00, accB0, 0, 0, 0);
                accB0 = __builtin_amdgcn_mfma_f32_32x32x16_bf16(A1.v, v01, accB0, 0, 0, 0);
                accB1 = __builtin_amdgcn_mfma_f32_32x32x16_bf16(A0.v, v10, accB1, 0, 0, 0);
                accB1 = __builtin_amdgcn_mfma_f32_32x32x16_bf16(A1.v, v11, accB1, 0, 0, 0);
            }
        }
    }

    // ---- epilogue: combine denominators, normalize, blend, store
    const float dAt = dA + __shfl_xor(dA, 32, 64);   // lane l: denom_A[query l&31]
    const float dBt = dB + __shfl_xor(dB, 32, 64);
    const float invA = __builtin_amdgcn_rcpf(dAt);
    const float invB = __builtin_amdgcn_rcpf(dBt);

#pragma unroll
    for (int r = 0; r < 16; r++) {
        const int cr = (r & 3) + 8 * (r >> 2) + 4 * h5;   // query row in wave tile
        const int j  = w * 32 + cr;                       // row within the 256-block
        const float ia = __shfl(invA, cr, 64);
        const float ib = __shfl(invB, cr, 64);
        float o0, o1;
        if (m == 0) {
            o0 = accB0[r] * ib;
            o1 = accB1[r] * ib;
        } else {
            const float alpha = (float)j * (1.0f / 255.0f);
            const float a0 = accA0[r] * ia, b0 = accB0[r] * ib;
            const float a1 = accA1[r] * ia, b1 = accB1[r] * ib;
            o0 = (1.0f - alpha) * a0 + alpha * b0;
            o1 = (1.0f - alpha) * a1 + alpha * b1;
        }
        float* orow = Ob + (size_t)(m * QB + j) * DD;
        orow[l31]      = o0;
        orow[32 + l31] = o1;
    }
}

extern "C" void kernel_launch(void* const* d_in, const int* in_sizes, int n_in,
                              void* d_out, int out_size, void* d_ws, size_t ws_size,
                              hipStream_t stream) {
    const float* Q = (const float*)d_in[0];
    const float* K = (const float*)d_in[1];
    const float* V = (const float*)d_in[2];
    const float* s = (const float*)d_in[3];
    float* out = (float*)d_out;
    dim3 grid(NB * NH * NM, 1, 1);   // 512
    dim3 block(512, 1, 1);
    hipLaunchKernelGGL(swa_kernel, grid, block, 0, stream, Q, K, V, s, out);
}